// Round 4
// baseline (522.910 us; speedup 1.0000x reference)
//
#include <hip/hip_runtime.h>
#include <math.h>

#define GG     384
#define HALFG  192
#define SZc    384
#define SYZc   147456
#define SXYZc  56623104
#define CC     128
#define PP     343
#define KK     125
// tabB: u32 tag-table for sp voxels, 2^20 slots = 4 MB
#define TBSLOTS (1 << 20)
#define TBMASK  (TBSLOTS - 1)
#define EMPTYB  0xFFFFFFFFu
// dense per-column z-bitmaps: B(=4) * 384 * 384 columns * 6 u64 = 28.3 MB
#define BMAXc   4
#define NCOL    (BMAXc * GG * GG)
// tabA: int2 dedupe table for grid voxels, 2^19 slots = 4 MB
#define TASLOTS (1 << 19)
#define TAMASK  (TASLOTS - 1)
#define CAPK   2048
#define CAPP   1024
#define EPSc   1e-5f

typedef unsigned long long u64;

__device__ __forceinline__ unsigned hash32(int code) {
    unsigned h = (unsigned)code;
    h ^= h >> 16; h *= 0x7feb352du;
    h ^= h >> 15; h *= 0x846ca68bu;
    h ^= h >> 16;
    return h;
}

// ---- fused: [0,nbA) blocks voxelize+dedupe grid points
//             (uid via LDS-aggregated per-block atomic: 686 global atomics total);
//             [nbA,..) blocks build sp tag table + dense column bitmaps ----
__global__ void k_buildInsert(const float* __restrict__ gp, int2* tabA, int* slotA,
                              int* nq, int* ucode, int N, int nbA,
                              const int4* __restrict__ spc4, unsigned* tabB,
                              u64* colBM, int Nv) {
    if (blockIdx.x < nbA) {
        __shared__ int lcnt, lbase;
        if (threadIdx.x == 0) lcnt = 0;
        __syncthreads();
        int i = blockIdx.x * 256 + threadIdx.x;
        int myloc = -1; unsigned myh = 0; int code = 0;
        if (i < N) {
            float4 g = ((const float4*)gp)[i];
            int b = (int)g.x;
            int vx = (int)floorf(g.y / 0.08f); vx = min(max(vx, -(HALFG - 1)), HALFG - 1);
            int vy = (int)floorf(g.z / 0.08f); vy = min(max(vy, -(HALFG - 1)), HALFG - 1);
            int vz = (int)floorf(g.w / 0.08f); vz = min(max(vz, -(HALFG - 1)), HALFG - 1);
            code = b * SXYZc + (vx + HALFG) * SYZc + (vy + HALFG) * SZc + (vz + HALFG);
            unsigned h = hash32(code) & TAMASK;
            while (true) {
                int old = atomicCAS(&tabA[h].x, -1, code);
                if (old == -1) { myloc = atomicAdd(&lcnt, 1); break; }
                if (old == code) break;
                h = (h + 1) & TAMASK;
            }
            myh = h;
            slotA[i] = (int)h;
        }
        __syncthreads();
        if (threadIdx.x == 0 && lcnt > 0) lbase = atomicAdd(nq, lcnt);
        __syncthreads();
        if (myloc >= 0) {
            int uid = lbase + myloc;
            tabA[myh].y = uid;
            ucode[uid] = code;
        }
    } else {
        int i = (blockIdx.x - nbA) * 256 + threadIdx.x;
        if (i >= Nv) return;
        int4 s = spc4[i];
        int b = s.x;
        int x = (s.y >> 1) + HALFG;
        int y = (s.z >> 1) + HALFG;
        int z = (s.w >> 1) + HALFG;
        int code = b * SXYZc + x * SYZc + y * SZc + z;
        unsigned h = hash32(code);
        unsigned slot = h & TBMASK;
        unsigned val = ((h >> 18) << 18) | (unsigned)i;
        while (true) {
            unsigned old = atomicCAS(&tabB[slot], EMPTYB, val);
            if (old == EMPTYB) break;
            slot = (slot + 1) & TBMASK;
        }
        int col = (b * GG + x) * GG + y;
        atomicOr(&colBM[(size_t)col * 6 + (z >> 6)], 1ull << (z & 63));
    }
}

// ---- probe: 25 columns per uid, dense bitmap index, exact resolve on hit;
//      hmark set via plain idempotent store (no counters, no CAS) ----
__global__ void k_probe(const int* __restrict__ ucode, const u64* __restrict__ colBM,
                        const unsigned* __restrict__ tabB, const int4* __restrict__ spc4,
                        int* hmark, int* cntk, int* bkUid, int* bkP,
                        const int* __restrict__ nqp, int N) {
    unsigned tid = blockIdx.x * 256u + threadIdx.x;
    if (tid >= (unsigned)N * 25u) return;
    unsigned uid = tid / 25u;
    if (uid >= (unsigned)(*nqp)) return;
    int c = (int)(tid - uid * 25u);      // c = dx*5 + dy
    unsigned code = (unsigned)ucode[uid];
    unsigned b = code / SXYZc; unsigned rem = code - b * SXYZc;
    int x = (int)(rem / SYZc); rem -= (unsigned)x * SYZc;
    int y = (int)(rem / SZc);
    int z = (int)(rem - (unsigned)y * SZc);
    int dx = c / 5, dy = c - dx * 5;
    int cx = x + dx - 2, cy = y + dy - 2;
    if ((unsigned)cx >= GG || (unsigned)cy >= GG) return;
    const u64* bm = colBM + (size_t)(((int)b * GG + cx) * GG + cy) * 6;
    int lo = max(z - 2, 0);
    int hi = min(z + 2, GG - 1);
    int width = hi - lo + 1;
    int i0 = lo >> 6, sh = lo & 63;
    u64 w = bm[i0] >> sh;
    if (sh + width > 64) w |= bm[i0 + 1] << (64 - sh);
    unsigned bits = (unsigned)(w & ((1ull << width) - 1ull));
    if (bits == 0) return;
    hmark[uid] = 1;
    int zbase = z - 2;
    while (bits) {
        int j = __builtin_ctz(bits);
        bits &= bits - 1;
        int tz = lo + j;
        int dz = tz - zbase;                           // 0..4
        int k = c * 5 + dz;
        int tcode = (int)b * SXYZc + cx * SYZc + cy * SZc + tz;
        unsigned h = hash32(tcode);
        unsigned slot = h & TBMASK;
        unsigned tag = h >> 18;
        while (true) {
            unsigned v = tabB[slot];
            if (v == EMPTYB) break;
            if ((v >> 18) == tag) {
                int row = (int)(v & 0x3FFFFu);
                int4 s = spc4[row];
                int rcode = s.x * SXYZc + ((s.y >> 1) + HALFG) * SYZc
                          + ((s.z >> 1) + HALFG) * SZc + ((s.w >> 1) + HALFG);
                if (rcode == tcode) {
                    int pos = atomicAdd(&cntk[k], 1);
                    if (pos < CAPK) { bkUid[k * CAPK + pos] = (int)uid; bkP[k * CAPK + pos] = row; }
                    break;
                }
            }
            slot = (slot + 1) & TBMASK;
        }
    }
}

// ---- build sparse (b,p,uid) pairs bucketed by p ----
__global__ void k_pairs(const int* __restrict__ slotA, const int2* __restrict__ tabA,
                        const int* __restrict__ hmark, int* pcnt, int* pairPack, int N) {
    int i = blockIdx.x * 256 + threadIdx.x;
    if (i >= N) return;
    int uid = tabA[slotA[i]].y;
    if (!hmark[uid]) return;
    int b = i / PP;
    int p = i - b * PP;
    int pos = atomicAdd(&pcnt[p], 1);
    if (pos < CAPP) pairPack[p * CAPP + pos] = (b << 18) | uid;
}

// ---- sparse conv: hits grouped by kernel offset, acc indexed by uid ----
__global__ __launch_bounds__(256) void k_conv(const float* __restrict__ spf,
        const float* __restrict__ W1, const int* __restrict__ cntk,
        const int* __restrict__ bkUid, const int* __restrict__ bkP, float* acc) {
    int k = blockIdx.x;
    int cob = blockIdx.y * 64;
    int t = threadIdx.x;
    int co = cob + (t & 63);
    int lane = t >> 6;                  // 0..3, 8 rows each
    int cnt = min(cntk[k], CAPK);
    __shared__ float fs[32][CC];
    __shared__ int hrS[32];
    const float* Wk = W1 + (size_t)k * CC * CC;
    for (int tile = blockIdx.z * 32; tile < cnt; tile += 32 * gridDim.z) {
        int nt = min(32, cnt - tile);
        if (t < nt) hrS[t] = bkUid[k * CAPK + tile + t];
        for (int e = t; e < 32 * CC; e += 256) {
            int r = e >> 7, cc = e & 127;
            fs[r][cc] = (r < nt) ? spf[(size_t)bkP[k * CAPK + tile + r] * CC + cc] : 0.f;
        }
        __syncthreads();
        float a[8] = {0.f, 0.f, 0.f, 0.f, 0.f, 0.f, 0.f, 0.f};
        for (int ci = 0; ci < CC; ci++) {
            float wv = Wk[(size_t)ci * CC + co];
            #pragma unroll
            for (int j = 0; j < 8; j++) a[j] += fs[lane * 8 + j][ci] * wv;
        }
        #pragma unroll
        for (int j = 0; j < 8; j++) {
            int r = lane * 8 + j;
            if (r < nt) atomicAdd(&acc[(size_t)hrS[r] * CC + co], a[j]);
        }
        __syncthreads();
    }
}

// ---- BN1 stats: ILP-4 float4 stream over all nq rows (non-hit rows are zero);
//      4 independent loads in flight per wave; register accumulate -> LDS reduce
//      -> 32 reducer threads do global atomics; last block computes scale/shift/c0 ----
__global__ __launch_bounds__(256) void k_stats(const float* __restrict__ acc,
                        float* gsum, float* gsumsq,
                        int* done, const float* __restrict__ g1, const float* __restrict__ b1,
                        float* scaleV, float* shiftV, float* c0v, const int* __restrict__ nqp) {
    int t = threadIdx.x;
    int nq = *nqp;
    long total4 = (long)nq * 32;           // float4 count
    const long S = (long)gridDim.x * 256;  // stride in float4s (multiple of 32)
    float s0=0.f,s1=0.f,s2=0.f,s3=0.f, q0=0.f,q1=0.f,q2=0.f,q3=0.f;
    const float4* a4 = (const float4*)acc;
    long e = (long)blockIdx.x * 256 + t;
    for (; e + 3 * S < total4; e += 4 * S) {
        float4 v0 = a4[e];
        float4 v1 = a4[e + S];
        float4 v2 = a4[e + 2 * S];
        float4 v3 = a4[e + 3 * S];
        s0 += v0.x; q0 += v0.x * v0.x; s1 += v0.y; q1 += v0.y * v0.y;
        s2 += v0.z; q2 += v0.z * v0.z; s3 += v0.w; q3 += v0.w * v0.w;
        s0 += v1.x; q0 += v1.x * v1.x; s1 += v1.y; q1 += v1.y * v1.y;
        s2 += v1.z; q2 += v1.z * v1.z; s3 += v1.w; q3 += v1.w * v1.w;
        s0 += v2.x; q0 += v2.x * v2.x; s1 += v2.y; q1 += v2.y * v2.y;
        s2 += v2.z; q2 += v2.z * v2.z; s3 += v2.w; q3 += v2.w * v2.w;
        s0 += v3.x; q0 += v3.x * v3.x; s1 += v3.y; q1 += v3.y * v3.y;
        s2 += v3.z; q2 += v3.z * v3.z; s3 += v3.w; q3 += v3.w * v3.w;
    }
    for (; e < total4; e += S) {
        float4 v = a4[e];
        s0 += v.x; q0 += v.x * v.x; s1 += v.y; q1 += v.y * v.y;
        s2 += v.z; q2 += v.z * v.z; s3 += v.w; q3 += v.w * v.w;
    }
    __shared__ float redA[256][4];
    __shared__ float redB[256][4];
    redA[t][0]=s0; redA[t][1]=s1; redA[t][2]=s2; redA[t][3]=s3;
    redB[t][0]=q0; redB[t][1]=q1; redB[t][2]=q2; redB[t][3]=q3;
    __syncthreads();
    if (t < 32) {
        // thread t owns channel quad t*4 .. t*4+3 (all strides multiple of 32 float4s)
        float as[4] = {0.f,0.f,0.f,0.f}, bs[4] = {0.f,0.f,0.f,0.f};
        for (int k = 0; k < 256; k += 32) {
            #pragma unroll
            for (int j = 0; j < 4; j++) { as[j] += redA[t + k][j]; bs[j] += redB[t + k][j]; }
        }
        #pragma unroll
        for (int j = 0; j < 4; j++) {
            atomicAdd(&gsum[t * 4 + j], as[j]);
            atomicAdd(&gsumsq[t * 4 + j], bs[j]);
        }
    }
    // last-block computes BN1 constants (coherent reads via atomicAdd(p, 0))
    __threadfence();
    __syncthreads();
    __shared__ int lastS;
    if (t == 0) lastS = (atomicAdd(done, 1) == gridDim.x - 1) ? 1 : 0;
    __syncthreads();
    if (lastS && t < 128) {
        float n = (float)max(nq, 1);
        float sum  = atomicAdd(&gsum[t], 0.f);
        float sums = atomicAdd(&gsumsq[t], 0.f);
        float mean = sum / n;
        float var = sums / n - mean * mean;
        float rs = 1.0f / sqrtf(var + EPSc);
        float scale = rs * g1[t];
        float shift = b1[t] - mean * scale;
        float c0 = shift;                          // bn(0) = shift
        c0 = c0 > 0.f ? c0 : expm1f(c0);
        scaleV[t] = scale; shiftV[t] = shift; c0v[t] = c0;
    }
}

// ---- sparse pooling: pairs grouped by p; elu(bn(acc))-c0 fused into LDS staging ----
__global__ __launch_bounds__(256) void k_pool(const float* __restrict__ acc,
        const float* __restrict__ W2, const int* __restrict__ pcnt,
        const int* __restrict__ pairPack,
        const float* __restrict__ scaleV, const float* __restrict__ shiftV,
        const float* __restrict__ c0v, float* pooled) {
    int p = blockIdx.x;
    int cob = blockIdx.y * 64;
    int t = threadIdx.x;
    int co = cob + (t & 63);
    int lane = t >> 6;
    int cnt = min(pcnt[p], CAPP);
    __shared__ float fs[32][CC];
    __shared__ int bS[32];
    __shared__ float scS[CC], shS[CC], c0S[CC];
    if (t < 128) { scS[t] = scaleV[t]; shS[t] = shiftV[t]; c0S[t] = c0v[t]; }
    __syncthreads();
    const float* Wp = W2 + (size_t)p * CC * CC;
    for (int tile = blockIdx.z * 32; tile < cnt; tile += 32 * gridDim.z) {
        int nt = min(32, cnt - tile);
        if (t < nt) bS[t] = pairPack[p * CAPP + tile + t] >> 18;
        for (int e = t; e < 32 * CC; e += 256) {
            int r = e >> 7, cc = e & 127;
            float v = 0.f;
            if (r < nt) {
                int uid = pairPack[p * CAPP + tile + r] & 0x3FFFF;
                float x = acc[(size_t)uid * CC + cc] * scS[cc] + shS[cc];
                x = x > 0.f ? x : expm1f(x);
                v = x - c0S[cc];
            }
            fs[r][cc] = v;
        }
        __syncthreads();
        float a[8] = {0.f, 0.f, 0.f, 0.f, 0.f, 0.f, 0.f, 0.f};
        for (int ci = 0; ci < CC; ci++) {
            float wv = Wp[(size_t)ci * CC + co];
            #pragma unroll
            for (int j = 0; j < 8; j++) a[j] += fs[lane * 8 + j][ci] * wv;
        }
        #pragma unroll
        for (int j = 0; j < 8; j++) {
            int r = lane * 8 + j;
            if (r < nt) atomicAdd(&pooled[(size_t)bS[r] * CC + co], a[j]);
        }
        __syncthreads();
    }
}

// ---- final BN over 512 rois ----
__global__ void k_bn2(const float* __restrict__ pooled, const float* __restrict__ g2,
                      const float* __restrict__ b2, float* out, int NB) {
    int d = blockIdx.x; int t = threadIdx.x;   // 64 threads = 1 wave
    float s = 0.f;
    for (int b = t; b < NB; b += 64) s += pooled[(size_t)b * CC + d];
    for (int o = 32; o >= 1; o >>= 1) s += __shfl_xor(s, o, 64);
    float mean = s / (float)NB;
    float s2 = 0.f;
    for (int b = t; b < NB; b += 64) { float v = pooled[(size_t)b * CC + d] - mean; s2 += v * v; }
    for (int o = 32; o >= 1; o >>= 1) s2 += __shfl_xor(s2, o, 64);
    float rs = 1.0f / sqrtf(s2 / (float)NB + EPSc);
    float gg = g2[d], bb = b2[d];
    for (int b = t; b < NB; b += 64)
        out[(size_t)b * CC + d] = (pooled[(size_t)b * CC + d] - mean) * rs * gg + bb;
}

extern "C" void kernel_launch(void* const* d_in, const int* in_sizes, int n_in,
                              void* d_out, int out_size, void* d_ws, size_t ws_size,
                              hipStream_t stream) {
    (void)n_in; (void)out_size; (void)ws_size;
    const int*   spc = (const int*)d_in[0];
    const float* spf = (const float*)d_in[1];
    const float* gp  = (const float*)d_in[2];
    const float* W1  = (const float*)d_in[3];
    const float* g1  = (const float*)d_in[4];
    const float* b1  = (const float*)d_in[5];
    const float* W2  = (const float*)d_in[6];
    const float* g2  = (const float*)d_in[7];
    const float* b2  = (const float*)d_in[8];
    int Nv = in_sizes[0] / 4;
    int N  = in_sizes[2] / 4;
    int NB = N / PP;
    float* out = (float*)d_out;

    char* w = (char*)d_ws;
    // ---- 0xFF-init region (one memset) ----
    unsigned* tabB = (unsigned*)w; w += (size_t)TBSLOTS * 4;   // 4 MB
    int2*     tabA = (int2*)w;     w += (size_t)TASLOTS * 8;   // 4 MB
    size_t ffbytes = (size_t)(w - (char*)d_ws);
    // ---- zero-init region (one memset) ----
    char* zero0 = w;
    int* nq   = (int*)w;  int* done = nq + 1;  w += 64;
    u64* colBM = (u64*)w;         w += (size_t)NCOL * 6 * 8;   // 28.3 MB
    int* cntk = (int*)w;          w += 128 * 4;
    int* pcnt = (int*)w;          w += 344 * 4;
    float* gsum   = (float*)w;    w += 128 * 4;
    float* gsumsq = (float*)w;    w += 128 * 4;
    int* hmark    = (int*)w;      w += (size_t)N * 4;
    float* pooled = (float*)w;    w += (size_t)NB * CC * 4;
    float* acc   = (float*)w;     w += (size_t)N * CC * 4;     // 89.9 MB
    size_t zbytes = (size_t)(w - zero0);
    // ---- written-before-read region ----
    float* scaleV = (float*)w;    w += 128 * 4;
    float* shiftV = (float*)w;    w += 128 * 4;
    float* c0v    = (float*)w;    w += 128 * 4;
    int* ucode   = (int*)w;       w += (size_t)N * 4;
    int* slotA   = (int*)w;       w += (size_t)N * 4;
    int* bkUid   = (int*)w;       w += (size_t)KK * CAPK * 4;
    int* bkP     = (int*)w;       w += (size_t)KK * CAPK * 4;
    int* pairPack= (int*)w;       w += (size_t)PP * CAPP * 4;

    hipMemsetAsync(tabB, 0xFF, ffbytes, stream);
    hipMemsetAsync(zero0, 0, zbytes, stream);

    int nbA = (N + 255) / 256;        // 686
    int nbB = (Nv + 255) / 256;       // 782
    k_buildInsert<<<nbA + nbB, 256, 0, stream>>>(gp, tabA, slotA, nq, ucode, N, nbA,
                                                 (const int4*)spc, tabB, colBM, Nv);
    long tot = (long)N * 25;
    k_probe  <<<(unsigned)((tot + 255) / 256), 256, 0, stream>>>(ucode, colBM, tabB,
                                                                 (const int4*)spc,
                                                                 hmark, cntk, bkUid, bkP, nq, N);
    k_pairs  <<<(N + 255) / 256, 256, 0, stream>>>(slotA, tabA, hmark, pcnt, pairPack, N);
    k_conv   <<<dim3(KK, 2, 4), 256, 0, stream>>>(spf, W1, cntk, bkUid, bkP, acc);
    k_stats  <<<1024, 256, 0, stream>>>(acc, gsum, gsumsq, done,
                                        g1, b1, scaleV, shiftV, c0v, nq);
    k_pool   <<<dim3(PP, 2, 2), 256, 0, stream>>>(acc, W2, pcnt, pairPack,
                                                  scaleV, shiftV, c0v, pooled);
    k_bn2    <<<CC, 64, 0, stream>>>(pooled, g2, b2, out, NB);
}

// Round 5
// 427.109 us; speedup vs baseline: 1.2243x; 1.2243x over previous
//
#include <hip/hip_runtime.h>
#include <math.h>

#define GG     384
#define HALFG  192
#define SZc    384
#define SYZc   147456
#define SXYZc  56623104
#define CC     128
#define PP     343
#define KK     125
// tabB: u32 tag-table for sp voxels, 2^20 slots = 4 MB
#define TBSLOTS (1 << 20)
#define TBMASK  (TBSLOTS - 1)
#define EMPTYB  0xFFFFFFFFu
// dense per-column z-bitmaps: B(=4) * 384 * 384 columns * 6 u64 = 28.3 MB
#define BMAXc   4
#define NCOL    (BMAXc * GG * GG)
// tabA: int2 dedupe table for grid voxels, 2^19 slots = 4 MB
#define TASLOTS (1 << 19)
#define TAMASK  (TASLOTS - 1)
#define CAPK   2048
#define CAPP   1024
#define EPSc   1e-5f

typedef unsigned long long u64;

__device__ __forceinline__ unsigned hash32(int code) {
    unsigned h = (unsigned)code;
    h ^= h >> 16; h *= 0x7feb352du;
    h ^= h >> 15; h *= 0x846ca68bu;
    h ^= h >> 16;
    return h;
}

// ---- fused: [0,nbA) blocks voxelize+dedupe grid points
//             (uid via LDS-aggregated per-block atomic: 686 global atomics total);
//             [nbA,..) blocks build sp tag table + dense column bitmaps ----
__global__ void k_buildInsert(const float* __restrict__ gp, int2* tabA, int* slotA,
                              int* nq, int* ucode, int N, int nbA,
                              const int4* __restrict__ spc4, unsigned* tabB,
                              u64* colBM, int Nv) {
    if (blockIdx.x < nbA) {
        __shared__ int lcnt, lbase;
        if (threadIdx.x == 0) lcnt = 0;
        __syncthreads();
        int i = blockIdx.x * 256 + threadIdx.x;
        int myloc = -1; unsigned myh = 0; int code = 0;
        if (i < N) {
            float4 g = ((const float4*)gp)[i];
            int b = (int)g.x;
            int vx = (int)floorf(g.y / 0.08f); vx = min(max(vx, -(HALFG - 1)), HALFG - 1);
            int vy = (int)floorf(g.z / 0.08f); vy = min(max(vy, -(HALFG - 1)), HALFG - 1);
            int vz = (int)floorf(g.w / 0.08f); vz = min(max(vz, -(HALFG - 1)), HALFG - 1);
            code = b * SXYZc + (vx + HALFG) * SYZc + (vy + HALFG) * SZc + (vz + HALFG);
            unsigned h = hash32(code) & TAMASK;
            while (true) {
                int old = atomicCAS(&tabA[h].x, -1, code);
                if (old == -1) { myloc = atomicAdd(&lcnt, 1); break; }
                if (old == code) break;
                h = (h + 1) & TAMASK;
            }
            myh = h;
            slotA[i] = (int)h;
        }
        __syncthreads();
        if (threadIdx.x == 0 && lcnt > 0) lbase = atomicAdd(nq, lcnt);
        __syncthreads();
        if (myloc >= 0) {
            int uid = lbase + myloc;
            tabA[myh].y = uid;
            ucode[uid] = code;
        }
    } else {
        int i = (blockIdx.x - nbA) * 256 + threadIdx.x;
        if (i >= Nv) return;
        int4 s = spc4[i];
        int b = s.x;
        int x = (s.y >> 1) + HALFG;
        int y = (s.z >> 1) + HALFG;
        int z = (s.w >> 1) + HALFG;
        int code = b * SXYZc + x * SYZc + y * SZc + z;
        unsigned h = hash32(code);
        unsigned slot = h & TBMASK;
        unsigned val = ((h >> 18) << 18) | (unsigned)i;
        while (true) {
            unsigned old = atomicCAS(&tabB[slot], EMPTYB, val);
            if (old == EMPTYB) break;
            slot = (slot + 1) & TBMASK;
        }
        int col = (b * GG + x) * GG + y;
        atomicOr(&colBM[(size_t)col * 6 + (z >> 6)], 1ull << (z & 63));
    }
}

// ---- probe: 25 columns per uid, dense bitmap index, exact resolve on hit;
//      hmark set via plain idempotent store (no counters, no CAS) ----
__global__ void k_probe(const int* __restrict__ ucode, const u64* __restrict__ colBM,
                        const unsigned* __restrict__ tabB, const int4* __restrict__ spc4,
                        int* hmark, int* cntk, int* bkUid, int* bkP,
                        const int* __restrict__ nqp, int N) {
    unsigned tid = blockIdx.x * 256u + threadIdx.x;
    if (tid >= (unsigned)N * 25u) return;
    unsigned uid = tid / 25u;
    if (uid >= (unsigned)(*nqp)) return;
    int c = (int)(tid - uid * 25u);      // c = dx*5 + dy
    unsigned code = (unsigned)ucode[uid];
    unsigned b = code / SXYZc; unsigned rem = code - b * SXYZc;
    int x = (int)(rem / SYZc); rem -= (unsigned)x * SYZc;
    int y = (int)(rem / SZc);
    int z = (int)(rem - (unsigned)y * SZc);
    int dx = c / 5, dy = c - dx * 5;
    int cx = x + dx - 2, cy = y + dy - 2;
    if ((unsigned)cx >= GG || (unsigned)cy >= GG) return;
    const u64* bm = colBM + (size_t)(((int)b * GG + cx) * GG + cy) * 6;
    int lo = max(z - 2, 0);
    int hi = min(z + 2, GG - 1);
    int width = hi - lo + 1;
    int i0 = lo >> 6, sh = lo & 63;
    u64 w = bm[i0] >> sh;
    if (sh + width > 64) w |= bm[i0 + 1] << (64 - sh);
    unsigned bits = (unsigned)(w & ((1ull << width) - 1ull));
    if (bits == 0) return;
    hmark[uid] = 1;
    int zbase = z - 2;
    while (bits) {
        int j = __builtin_ctz(bits);
        bits &= bits - 1;
        int tz = lo + j;
        int dz = tz - zbase;                           // 0..4
        int k = c * 5 + dz;
        int tcode = (int)b * SXYZc + cx * SYZc + cy * SZc + tz;
        unsigned h = hash32(tcode);
        unsigned slot = h & TBMASK;
        unsigned tag = h >> 18;
        while (true) {
            unsigned v = tabB[slot];
            if (v == EMPTYB) break;
            if ((v >> 18) == tag) {
                int row = (int)(v & 0x3FFFFu);
                int4 s = spc4[row];
                int rcode = s.x * SXYZc + ((s.y >> 1) + HALFG) * SYZc
                          + ((s.z >> 1) + HALFG) * SZc + ((s.w >> 1) + HALFG);
                if (rcode == tcode) {
                    int pos = atomicAdd(&cntk[k], 1);
                    if (pos < CAPK) { bkUid[k * CAPK + pos] = (int)uid; bkP[k * CAPK + pos] = row; }
                    break;
                }
            }
            slot = (slot + 1) & TBMASK;
        }
    }
}

// ---- fused: [0,nbU) blocks compact hit uids -> hitList (LDS-aggregated counter)
//             and zero acc rows of hits (so conv atomics start from 0);
//             [nbU,..) blocks build sparse (b,p,uid) pairs bucketed by p ----
__global__ void k_hitPairs(const int* __restrict__ hmark, int* hitList, int* nh,
                           float* acc, const int* __restrict__ nqp, int nbU,
                           const int* __restrict__ slotA, const int2* __restrict__ tabA,
                           int* pcnt, int* pairPack, int N) {
    if (blockIdx.x < nbU) {
        __shared__ int lcnt, lbase;
        if (threadIdx.x == 0) lcnt = 0;
        __syncthreads();
        int i = blockIdx.x * 256 + threadIdx.x;
        int myloc = -1;
        if (i < *nqp && hmark[i]) myloc = atomicAdd(&lcnt, 1);
        __syncthreads();
        if (threadIdx.x == 0 && lcnt > 0) lbase = atomicAdd(nh, lcnt);
        __syncthreads();
        if (myloc >= 0) {
            hitList[lbase + myloc] = i;
            float4* a4 = (float4*)(acc + (size_t)i * CC);
            float4 z4 = make_float4(0.f, 0.f, 0.f, 0.f);
            #pragma unroll
            for (int c = 0; c < CC / 4; c++) a4[c] = z4;
        }
    } else {
        int i = (blockIdx.x - nbU) * 256 + threadIdx.x;
        if (i >= N) return;
        int uid = tabA[slotA[i]].y;
        if (!hmark[uid]) return;
        int b = i / PP;
        int p = i - b * PP;
        int pos = atomicAdd(&pcnt[p], 1);
        if (pos < CAPP) pairPack[p * CAPP + pos] = (b << 18) | uid;
    }
}

// ---- sparse conv: hits grouped by kernel offset, acc indexed by uid ----
__global__ __launch_bounds__(256) void k_conv(const float* __restrict__ spf,
        const float* __restrict__ W1, const int* __restrict__ cntk,
        const int* __restrict__ bkUid, const int* __restrict__ bkP, float* acc) {
    int k = blockIdx.x;
    int cob = blockIdx.y * 64;
    int t = threadIdx.x;
    int co = cob + (t & 63);
    int lane = t >> 6;                  // 0..3, 8 rows each
    int cnt = min(cntk[k], CAPK);
    __shared__ float fs[32][CC];
    __shared__ int hrS[32];
    const float* Wk = W1 + (size_t)k * CC * CC;
    for (int tile = blockIdx.z * 32; tile < cnt; tile += 32 * gridDim.z) {
        int nt = min(32, cnt - tile);
        if (t < nt) hrS[t] = bkUid[k * CAPK + tile + t];
        for (int e = t; e < 32 * CC; e += 256) {
            int r = e >> 7, cc = e & 127;
            fs[r][cc] = (r < nt) ? spf[(size_t)bkP[k * CAPK + tile + r] * CC + cc] : 0.f;
        }
        __syncthreads();
        float a[8] = {0.f, 0.f, 0.f, 0.f, 0.f, 0.f, 0.f, 0.f};
        for (int ci = 0; ci < CC; ci++) {
            float wv = Wk[(size_t)ci * CC + co];
            #pragma unroll
            for (int j = 0; j < 8; j++) a[j] += fs[lane * 8 + j][ci] * wv;
        }
        #pragma unroll
        for (int j = 0; j < 8; j++) {
            int r = lane * 8 + j;
            if (r < nt) atomicAdd(&acc[(size_t)hrS[r] * CC + co], a[j]);
        }
        __syncthreads();
    }
}

// ---- BN1 stats over compact hit list (r0-measured form);
//      last block computes scale/shift/c0 ----
__global__ void k_stats(const float* __restrict__ acc, const int* __restrict__ hitList,
                        float* gsum, float* gsumsq, const int* __restrict__ nhp,
                        int* done, const float* __restrict__ g1, const float* __restrict__ b1,
                        float* scaleV, float* shiftV, float* c0v, const int* __restrict__ nqp) {
    int t = threadIdx.x; int c = t & 127; int half = t >> 7;
    int nh = *nhp;
    float s = 0.f, s2 = 0.f;
    for (int j = blockIdx.x * 2 + half; j < nh; j += gridDim.x * 2) {
        int r = hitList[j];
        float v = acc[(size_t)r * CC + c];
        s += v; s2 += v * v;
    }
    __shared__ float red[256];
    red[t] = s; __syncthreads();
    if (half == 0) atomicAdd(&gsum[c], s + red[t + 128]);
    __syncthreads();
    red[t] = s2; __syncthreads();
    if (half == 0) atomicAdd(&gsumsq[c], s2 + red[t + 128]);
    // last-block computes BN1 constants (coherent reads via atomicAdd(p, 0))
    __threadfence();
    __syncthreads();
    __shared__ int lastS;
    if (t == 0) lastS = (atomicAdd(done, 1) == gridDim.x - 1) ? 1 : 0;
    __syncthreads();
    if (lastS && t < 128) {
        float n = (float)max(*nqp, 1);
        float sum  = atomicAdd(&gsum[t], 0.f);
        float sums = atomicAdd(&gsumsq[t], 0.f);
        float mean = sum / n;
        float var = sums / n - mean * mean;
        float rs = 1.0f / sqrtf(var + EPSc);
        float scale = rs * g1[t];
        float shift = b1[t] - mean * scale;
        float c0 = shift;                          // bn(0) = shift
        c0 = c0 > 0.f ? c0 : expm1f(c0);
        scaleV[t] = scale; shiftV[t] = shift; c0v[t] = c0;
    }
}

// ---- sparse pooling: pairs grouped by p; elu(bn(acc))-c0 fused into LDS staging ----
__global__ __launch_bounds__(256) void k_pool(const float* __restrict__ acc,
        const float* __restrict__ W2, const int* __restrict__ pcnt,
        const int* __restrict__ pairPack,
        const float* __restrict__ scaleV, const float* __restrict__ shiftV,
        const float* __restrict__ c0v, float* pooled) {
    int p = blockIdx.x;
    int cob = blockIdx.y * 64;
    int t = threadIdx.x;
    int co = cob + (t & 63);
    int lane = t >> 6;
    int cnt = min(pcnt[p], CAPP);
    __shared__ float fs[32][CC];
    __shared__ int bS[32];
    __shared__ float scS[CC], shS[CC], c0S[CC];
    if (t < 128) { scS[t] = scaleV[t]; shS[t] = shiftV[t]; c0S[t] = c0v[t]; }
    __syncthreads();
    const float* Wp = W2 + (size_t)p * CC * CC;
    for (int tile = blockIdx.z * 32; tile < cnt; tile += 32 * gridDim.z) {
        int nt = min(32, cnt - tile);
        if (t < nt) bS[t] = pairPack[p * CAPP + tile + t] >> 18;
        for (int e = t; e < 32 * CC; e += 256) {
            int r = e >> 7, cc = e & 127;
            float v = 0.f;
            if (r < nt) {
                int uid = pairPack[p * CAPP + tile + r] & 0x3FFFF;
                float x = acc[(size_t)uid * CC + cc] * scS[cc] + shS[cc];
                x = x > 0.f ? x : expm1f(x);
                v = x - c0S[cc];
            }
            fs[r][cc] = v;
        }
        __syncthreads();
        float a[8] = {0.f, 0.f, 0.f, 0.f, 0.f, 0.f, 0.f, 0.f};
        for (int ci = 0; ci < CC; ci++) {
            float wv = Wp[(size_t)ci * CC + co];
            #pragma unroll
            for (int j = 0; j < 8; j++) a[j] += fs[lane * 8 + j][ci] * wv;
        }
        #pragma unroll
        for (int j = 0; j < 8; j++) {
            int r = lane * 8 + j;
            if (r < nt) atomicAdd(&pooled[(size_t)bS[r] * CC + co], a[j]);
        }
        __syncthreads();
    }
}

// ---- final BN over 512 rois ----
__global__ void k_bn2(const float* __restrict__ pooled, const float* __restrict__ g2,
                      const float* __restrict__ b2, float* out, int NB) {
    int d = blockIdx.x; int t = threadIdx.x;   // 64 threads = 1 wave
    float s = 0.f;
    for (int b = t; b < NB; b += 64) s += pooled[(size_t)b * CC + d];
    for (int o = 32; o >= 1; o >>= 1) s += __shfl_xor(s, o, 64);
    float mean = s / (float)NB;
    float s2 = 0.f;
    for (int b = t; b < NB; b += 64) { float v = pooled[(size_t)b * CC + d] - mean; s2 += v * v; }
    for (int o = 32; o >= 1; o >>= 1) s2 += __shfl_xor(s2, o, 64);
    float rs = 1.0f / sqrtf(s2 / (float)NB + EPSc);
    float gg = g2[d], bb = b2[d];
    for (int b = t; b < NB; b += 64)
        out[(size_t)b * CC + d] = (pooled[(size_t)b * CC + d] - mean) * rs * gg + bb;
}

extern "C" void kernel_launch(void* const* d_in, const int* in_sizes, int n_in,
                              void* d_out, int out_size, void* d_ws, size_t ws_size,
                              hipStream_t stream) {
    (void)n_in; (void)out_size; (void)ws_size;
    const int*   spc = (const int*)d_in[0];
    const float* spf = (const float*)d_in[1];
    const float* gp  = (const float*)d_in[2];
    const float* W1  = (const float*)d_in[3];
    const float* g1  = (const float*)d_in[4];
    const float* b1  = (const float*)d_in[5];
    const float* W2  = (const float*)d_in[6];
    const float* g2  = (const float*)d_in[7];
    const float* b2  = (const float*)d_in[8];
    int Nv = in_sizes[0] / 4;
    int N  = in_sizes[2] / 4;
    int NB = N / PP;
    float* out = (float*)d_out;

    char* w = (char*)d_ws;
    // ---- 0xFF-init region (one memset) ----
    unsigned* tabB = (unsigned*)w; w += (size_t)TBSLOTS * 4;   // 4 MB
    int2*     tabA = (int2*)w;     w += (size_t)TASLOTS * 8;   // 4 MB
    size_t ffbytes = (size_t)(w - (char*)d_ws);
    // ---- zero-init region (one memset) ----
    char* zero0 = w;
    int* nq   = (int*)w;  int* nh = nq + 1;  int* done = nq + 2;  w += 64;
    u64* colBM = (u64*)w;         w += (size_t)NCOL * 6 * 8;   // 28.3 MB
    int* cntk = (int*)w;          w += 128 * 4;
    int* pcnt = (int*)w;          w += 344 * 4;
    float* gsum   = (float*)w;    w += 128 * 4;
    float* gsumsq = (float*)w;    w += 128 * 4;
    int* hmark    = (int*)w;      w += (size_t)N * 4;
    float* pooled = (float*)w;    w += (size_t)NB * CC * 4;
    size_t zbytes = (size_t)(w - zero0);
    // ---- written-before-read region ----
    float* scaleV = (float*)w;    w += 128 * 4;
    float* shiftV = (float*)w;    w += 128 * 4;
    float* c0v    = (float*)w;    w += 128 * 4;
    int* hitList = (int*)w;       w += (size_t)N * 4;
    int* ucode   = (int*)w;       w += (size_t)N * 4;
    int* slotA   = (int*)w;       w += (size_t)N * 4;
    int* bkUid   = (int*)w;       w += (size_t)KK * CAPK * 4;
    int* bkP     = (int*)w;       w += (size_t)KK * CAPK * 4;
    int* pairPack= (int*)w;       w += (size_t)PP * CAPP * 4;
    float* acc   = (float*)w;     w += (size_t)N * CC * 4;     // 89.9 MB

    hipMemsetAsync(tabB, 0xFF, ffbytes, stream);
    hipMemsetAsync(zero0, 0, zbytes, stream);

    int nbA = (N + 255) / 256;        // 686
    int nbB = (Nv + 255) / 256;       // 782
    k_buildInsert<<<nbA + nbB, 256, 0, stream>>>(gp, tabA, slotA, nq, ucode, N, nbA,
                                                 (const int4*)spc, tabB, colBM, Nv);
    long tot = (long)N * 25;
    k_probe  <<<(unsigned)((tot + 255) / 256), 256, 0, stream>>>(ucode, colBM, tabB,
                                                                 (const int4*)spc,
                                                                 hmark, cntk, bkUid, bkP, nq, N);
    int nbU = (N + 255) / 256;        // covers all possible uids
    k_hitPairs<<<nbU + nbA, 256, 0, stream>>>(hmark, hitList, nh, acc, nq, nbU,
                                              slotA, tabA, pcnt, pairPack, N);
    k_conv   <<<dim3(KK, 2, 4), 256, 0, stream>>>(spf, W1, cntk, bkUid, bkP, acc);
    k_stats  <<<1024, 256, 0, stream>>>(acc, hitList, gsum, gsumsq, nh, done,
                                        g1, b1, scaleV, shiftV, c0v, nq);
    k_pool   <<<dim3(PP, 2, 2), 256, 0, stream>>>(acc, W2, pcnt, pairPack,
                                                  scaleV, shiftV, c0v, pooled);
    k_bn2    <<<CC, 64, 0, stream>>>(pooled, g2, b2, out, NB);
}

// Round 6
// 349.820 us; speedup vs baseline: 1.4948x; 1.2209x over previous
//
#include <hip/hip_runtime.h>
#include <math.h>

#define GG     384
#define HALFG  192
#define SZc    384
#define SYZc   147456
#define SXYZc  56623104
#define CC     128
#define PP     343
#define KK     125
// tabB: u32 tag-table for sp voxels, 2^20 slots = 4 MB
#define TBSLOTS (1 << 20)
#define TBMASK  (TBSLOTS - 1)
#define EMPTYB  0xFFFFFFFFu
// dense per-column z-bitmaps: B(=4) * 384 * 384 columns * 6 u64 = 28.3 MB
#define BMAXc   4
#define NCOL    (BMAXc * GG * GG)
// tabA: int2 dedupe table for grid voxels, 2^19 slots = 4 MB
#define TASLOTS (1 << 19)
#define TAMASK  (TASLOTS - 1)
#define CAPK   2048
#define CAPP   1024
#define EPSc   1e-5f
// pad hot atomic counters to one 64B line each
#define PAD    16

typedef unsigned long long u64;

__device__ __forceinline__ unsigned hash32(int code) {
    unsigned h = (unsigned)code;
    h ^= h >> 16; h *= 0x7feb352du;
    h ^= h >> 15; h *= 0x846ca68bu;
    h ^= h >> 16;
    return h;
}

// ---- fused: [0,nbA) blocks voxelize+dedupe grid points
//             (uid via LDS-aggregated per-block atomic: 686 global atomics total);
//             [nbA,..) blocks build sp tag table + dense column bitmaps ----
__global__ void k_buildInsert(const float* __restrict__ gp, int2* tabA, int* slotA,
                              int* nq, int* ucode, int N, int nbA,
                              const int4* __restrict__ spc4, unsigned* tabB,
                              u64* colBM, int Nv) {
    if (blockIdx.x < nbA) {
        __shared__ int lcnt, lbase;
        if (threadIdx.x == 0) lcnt = 0;
        __syncthreads();
        int i = blockIdx.x * 256 + threadIdx.x;
        int myloc = -1; unsigned myh = 0; int code = 0;
        if (i < N) {
            float4 g = ((const float4*)gp)[i];
            int b = (int)g.x;
            int vx = (int)floorf(g.y / 0.08f); vx = min(max(vx, -(HALFG - 1)), HALFG - 1);
            int vy = (int)floorf(g.z / 0.08f); vy = min(max(vy, -(HALFG - 1)), HALFG - 1);
            int vz = (int)floorf(g.w / 0.08f); vz = min(max(vz, -(HALFG - 1)), HALFG - 1);
            code = b * SXYZc + (vx + HALFG) * SYZc + (vy + HALFG) * SZc + (vz + HALFG);
            unsigned h = hash32(code) & TAMASK;
            while (true) {
                int old = atomicCAS(&tabA[h].x, -1, code);
                if (old == -1) { myloc = atomicAdd(&lcnt, 1); break; }
                if (old == code) break;
                h = (h + 1) & TAMASK;
            }
            myh = h;
            slotA[i] = (int)h;
        }
        __syncthreads();
        if (threadIdx.x == 0 && lcnt > 0) lbase = atomicAdd(nq, lcnt);
        __syncthreads();
        if (myloc >= 0) {
            int uid = lbase + myloc;
            tabA[myh].y = uid;
            ucode[uid] = code;
        }
    } else {
        int i = (blockIdx.x - nbA) * 256 + threadIdx.x;
        if (i >= Nv) return;
        int4 s = spc4[i];
        int b = s.x;
        int x = (s.y >> 1) + HALFG;
        int y = (s.z >> 1) + HALFG;
        int z = (s.w >> 1) + HALFG;
        int code = b * SXYZc + x * SYZc + y * SZc + z;
        unsigned h = hash32(code);
        unsigned slot = h & TBMASK;
        unsigned val = ((h >> 18) << 18) | (unsigned)i;
        while (true) {
            unsigned old = atomicCAS(&tabB[slot], EMPTYB, val);
            if (old == EMPTYB) break;
            slot = (slot + 1) & TBMASK;
        }
        int col = (b * GG + x) * GG + y;
        atomicOr(&colBM[(size_t)col * 6 + (z >> 6)], 1ull << (z & 63));
    }
}

// ---- probe: 25 columns per uid, dense bitmap index, exact resolve on hit;
//      hmark set via plain idempotent store; cntk padded to 64B/counter ----
__global__ void k_probe(const int* __restrict__ ucode, const u64* __restrict__ colBM,
                        const unsigned* __restrict__ tabB, const int4* __restrict__ spc4,
                        int* hmark, int* cntk, int* bkUid, int* bkP,
                        const int* __restrict__ nqp, int N) {
    unsigned tid = blockIdx.x * 256u + threadIdx.x;
    if (tid >= (unsigned)N * 25u) return;
    unsigned uid = tid / 25u;
    if (uid >= (unsigned)(*nqp)) return;
    int c = (int)(tid - uid * 25u);      // c = dx*5 + dy
    unsigned code = (unsigned)ucode[uid];
    unsigned b = code / SXYZc; unsigned rem = code - b * SXYZc;
    int x = (int)(rem / SYZc); rem -= (unsigned)x * SYZc;
    int y = (int)(rem / SZc);
    int z = (int)(rem - (unsigned)y * SZc);
    int dx = c / 5, dy = c - dx * 5;
    int cx = x + dx - 2, cy = y + dy - 2;
    if ((unsigned)cx >= GG || (unsigned)cy >= GG) return;
    const u64* bm = colBM + (size_t)(((int)b * GG + cx) * GG + cy) * 6;
    int lo = max(z - 2, 0);
    int hi = min(z + 2, GG - 1);
    int width = hi - lo + 1;
    int i0 = lo >> 6, sh = lo & 63;
    u64 w = bm[i0] >> sh;
    if (sh + width > 64) w |= bm[i0 + 1] << (64 - sh);
    unsigned bits = (unsigned)(w & ((1ull << width) - 1ull));
    if (bits == 0) return;
    hmark[uid] = 1;
    int zbase = z - 2;
    while (bits) {
        int j = __builtin_ctz(bits);
        bits &= bits - 1;
        int tz = lo + j;
        int dz = tz - zbase;                           // 0..4
        int k = c * 5 + dz;
        int tcode = (int)b * SXYZc + cx * SYZc + cy * SZc + tz;
        unsigned h = hash32(tcode);
        unsigned slot = h & TBMASK;
        unsigned tag = h >> 18;
        while (true) {
            unsigned v = tabB[slot];
            if (v == EMPTYB) break;
            if ((v >> 18) == tag) {
                int row = (int)(v & 0x3FFFFu);
                int4 s = spc4[row];
                int rcode = s.x * SXYZc + ((s.y >> 1) + HALFG) * SYZc
                          + ((s.z >> 1) + HALFG) * SZc + ((s.w >> 1) + HALFG);
                if (rcode == tcode) {
                    int pos = atomicAdd(&cntk[k * PAD], 1);
                    if (pos < CAPK) { bkUid[k * CAPK + pos] = (int)uid; bkP[k * CAPK + pos] = row; }
                    break;
                }
            }
            slot = (slot + 1) & TBMASK;
        }
    }
}

// ---- fused: [0,nbU) blocks compact hit uids -> hitList (LDS-aggregated counter)
//             and zero acc rows of hits (so conv atomics start from 0);
//             [nbU,..) blocks build sparse (b,p,uid) pairs bucketed by p ----
__global__ void k_hitPairs(const int* __restrict__ hmark, int* hitList, int* nh,
                           float* acc, const int* __restrict__ nqp, int nbU,
                           const int* __restrict__ slotA, const int2* __restrict__ tabA,
                           int* pcnt, int* pairPack, int N) {
    if (blockIdx.x < nbU) {
        __shared__ int lcnt, lbase;
        if (threadIdx.x == 0) lcnt = 0;
        __syncthreads();
        int i = blockIdx.x * 256 + threadIdx.x;
        int myloc = -1;
        if (i < *nqp && hmark[i]) myloc = atomicAdd(&lcnt, 1);
        __syncthreads();
        if (threadIdx.x == 0 && lcnt > 0) lbase = atomicAdd(nh, lcnt);
        __syncthreads();
        if (myloc >= 0) {
            hitList[lbase + myloc] = i;
            float4* a4 = (float4*)(acc + (size_t)i * CC);
            float4 z4 = make_float4(0.f, 0.f, 0.f, 0.f);
            #pragma unroll
            for (int c = 0; c < CC / 4; c++) a4[c] = z4;
        }
    } else {
        int i = (blockIdx.x - nbU) * 256 + threadIdx.x;
        if (i >= N) return;
        int uid = tabA[slotA[i]].y;
        if (!hmark[uid]) return;
        int b = i / PP;
        int p = i - b * PP;
        int pos = atomicAdd(&pcnt[p * PAD], 1);
        if (pos < CAPP) pairPack[p * CAPP + pos] = (b << 18) | uid;
    }
}

// ---- sparse conv: hits grouped by kernel offset, acc indexed by uid ----
__global__ __launch_bounds__(256) void k_conv(const float* __restrict__ spf,
        const float* __restrict__ W1, const int* __restrict__ cntk,
        const int* __restrict__ bkUid, const int* __restrict__ bkP, float* acc) {
    int k = blockIdx.x;
    int cob = blockIdx.y * 64;
    int t = threadIdx.x;
    int co = cob + (t & 63);
    int lane = t >> 6;                  // 0..3, 8 rows each
    int cnt = min(cntk[k * PAD], CAPK);
    __shared__ float fs[32][CC];
    __shared__ int hrS[32];
    const float* Wk = W1 + (size_t)k * CC * CC;
    for (int tile = blockIdx.z * 32; tile < cnt; tile += 32 * gridDim.z) {
        int nt = min(32, cnt - tile);
        if (t < nt) hrS[t] = bkUid[k * CAPK + tile + t];
        for (int e = t; e < 32 * CC; e += 256) {
            int r = e >> 7, cc = e & 127;
            fs[r][cc] = (r < nt) ? spf[(size_t)bkP[k * CAPK + tile + r] * CC + cc] : 0.f;
        }
        __syncthreads();
        float a[8] = {0.f, 0.f, 0.f, 0.f, 0.f, 0.f, 0.f, 0.f};
        for (int ci = 0; ci < CC; ci++) {
            float wv = Wk[(size_t)ci * CC + co];
            #pragma unroll
            for (int j = 0; j < 8; j++) a[j] += fs[lane * 8 + j][ci] * wv;
        }
        #pragma unroll
        for (int j = 0; j < 8; j++) {
            int r = lane * 8 + j;
            if (r < nt) atomicAdd(&acc[(size_t)hrS[r] * CC + co], a[j]);
        }
        __syncthreads();
    }
}

// ---- BN1 stats over compact hit list; padded per-line atomic targets;
//      t0-only fence; last block computes scale/shift/c0 ----
__global__ void k_stats(const float* __restrict__ acc, const int* __restrict__ hitList,
                        float* gsum, float* gsumsq, const int* __restrict__ nhp,
                        int* done, const float* __restrict__ g1, const float* __restrict__ b1,
                        float* scaleV, float* shiftV, float* c0v, const int* __restrict__ nqp) {
    int t = threadIdx.x; int c = t & 127; int half = t >> 7;
    int nh = *nhp;
    float s = 0.f, s2 = 0.f;
    for (int j = blockIdx.x * 2 + half; j < nh; j += gridDim.x * 2) {
        int r = hitList[j];
        float v = acc[(size_t)r * CC + c];
        s += v; s2 += v * v;
    }
    __shared__ float red[256];
    red[t] = s; __syncthreads();
    if (half == 0) atomicAdd(&gsum[c * PAD], s + red[t + 128]);
    __syncthreads();
    red[t] = s2; __syncthreads();
    if (half == 0) atomicAdd(&gsumsq[c * PAD], s2 + red[t + 128]);
    // all block atomics drained by the barrier below; t0 does release+count
    __syncthreads();
    __shared__ int lastS;
    if (t == 0) {
        __threadfence();
        lastS = (atomicAdd(done, 1) == gridDim.x - 1) ? 1 : 0;
    }
    __syncthreads();
    if (lastS && t < 128) {
        float n = (float)max(*nqp, 1);
        float sum  = atomicAdd(&gsum[t * PAD], 0.f);
        float sums = atomicAdd(&gsumsq[t * PAD], 0.f);
        float mean = sum / n;
        float var = sums / n - mean * mean;
        float rs = 1.0f / sqrtf(var + EPSc);
        float scale = rs * g1[t];
        float shift = b1[t] - mean * scale;
        float c0 = shift;                          // bn(0) = shift
        c0 = c0 > 0.f ? c0 : expm1f(c0);
        scaleV[t] = scale; shiftV[t] = shift; c0v[t] = c0;
    }
}

// ---- sparse pooling: pairs grouped by p; elu(bn(acc))-c0 fused into LDS staging ----
__global__ __launch_bounds__(256) void k_pool(const float* __restrict__ acc,
        const float* __restrict__ W2, const int* __restrict__ pcnt,
        const int* __restrict__ pairPack,
        const float* __restrict__ scaleV, const float* __restrict__ shiftV,
        const float* __restrict__ c0v, float* pooled) {
    int p = blockIdx.x;
    int cob = blockIdx.y * 64;
    int t = threadIdx.x;
    int co = cob + (t & 63);
    int lane = t >> 6;
    int cnt = min(pcnt[p * PAD], CAPP);
    __shared__ float fs[32][CC];
    __shared__ int bS[32];
    __shared__ float scS[CC], shS[CC], c0S[CC];
    if (t < 128) { scS[t] = scaleV[t]; shS[t] = shiftV[t]; c0S[t] = c0v[t]; }
    __syncthreads();
    const float* Wp = W2 + (size_t)p * CC * CC;
    for (int tile = blockIdx.z * 32; tile < cnt; tile += 32 * gridDim.z) {
        int nt = min(32, cnt - tile);
        if (t < nt) bS[t] = pairPack[p * CAPP + tile + t] >> 18;
        for (int e = t; e < 32 * CC; e += 256) {
            int r = e >> 7, cc = e & 127;
            float v = 0.f;
            if (r < nt) {
                int uid = pairPack[p * CAPP + tile + r] & 0x3FFFF;
                float x = acc[(size_t)uid * CC + cc] * scS[cc] + shS[cc];
                x = x > 0.f ? x : expm1f(x);
                v = x - c0S[cc];
            }
            fs[r][cc] = v;
        }
        __syncthreads();
        float a[8] = {0.f, 0.f, 0.f, 0.f, 0.f, 0.f, 0.f, 0.f};
        for (int ci = 0; ci < CC; ci++) {
            float wv = Wp[(size_t)ci * CC + co];
            #pragma unroll
            for (int j = 0; j < 8; j++) a[j] += fs[lane * 8 + j][ci] * wv;
        }
        #pragma unroll
        for (int j = 0; j < 8; j++) {
            int r = lane * 8 + j;
            if (r < nt) atomicAdd(&pooled[(size_t)bS[r] * CC + co], a[j]);
        }
        __syncthreads();
    }
}

// ---- final BN over 512 rois ----
__global__ void k_bn2(const float* __restrict__ pooled, const float* __restrict__ g2,
                      const float* __restrict__ b2, float* out, int NB) {
    int d = blockIdx.x; int t = threadIdx.x;   // 64 threads = 1 wave
    float s = 0.f;
    for (int b = t; b < NB; b += 64) s += pooled[(size_t)b * CC + d];
    for (int o = 32; o >= 1; o >>= 1) s += __shfl_xor(s, o, 64);
    float mean = s / (float)NB;
    float s2 = 0.f;
    for (int b = t; b < NB; b += 64) { float v = pooled[(size_t)b * CC + d] - mean; s2 += v * v; }
    for (int o = 32; o >= 1; o >>= 1) s2 += __shfl_xor(s2, o, 64);
    float rs = 1.0f / sqrtf(s2 / (float)NB + EPSc);
    float gg = g2[d], bb = b2[d];
    for (int b = t; b < NB; b += 64)
        out[(size_t)b * CC + d] = (pooled[(size_t)b * CC + d] - mean) * rs * gg + bb;
}

extern "C" void kernel_launch(void* const* d_in, const int* in_sizes, int n_in,
                              void* d_out, int out_size, void* d_ws, size_t ws_size,
                              hipStream_t stream) {
    (void)n_in; (void)out_size; (void)ws_size;
    const int*   spc = (const int*)d_in[0];
    const float* spf = (const float*)d_in[1];
    const float* gp  = (const float*)d_in[2];
    const float* W1  = (const float*)d_in[3];
    const float* g1  = (const float*)d_in[4];
    const float* b1  = (const float*)d_in[5];
    const float* W2  = (const float*)d_in[6];
    const float* g2  = (const float*)d_in[7];
    const float* b2  = (const float*)d_in[8];
    int Nv = in_sizes[0] / 4;
    int N  = in_sizes[2] / 4;
    int NB = N / PP;
    float* out = (float*)d_out;

    char* w = (char*)d_ws;
    // ---- 0xFF-init region (one memset) ----
    unsigned* tabB = (unsigned*)w; w += (size_t)TBSLOTS * 4;   // 4 MB
    int2*     tabA = (int2*)w;     w += (size_t)TASLOTS * 8;   // 4 MB
    size_t ffbytes = (size_t)(w - (char*)d_ws);
    // ---- zero-init region (one memset) ----
    char* zero0 = w;
    int* nq   = (int*)w;  int* nh = nq + 1;  int* done = nq + 2;  w += 64;
    u64* colBM = (u64*)w;         w += (size_t)NCOL * 6 * 8;   // 28.3 MB
    int* cntk = (int*)w;          w += 128 * PAD * 4;
    int* pcnt = (int*)w;          w += 344 * PAD * 4;
    float* gsum   = (float*)w;    w += 128 * PAD * 4;
    float* gsumsq = (float*)w;    w += 128 * PAD * 4;
    int* hmark    = (int*)w;      w += (size_t)N * 4;
    float* pooled = (float*)w;    w += (size_t)NB * CC * 4;
    size_t zbytes = (size_t)(w - zero0);
    // ---- written-before-read region ----
    float* scaleV = (float*)w;    w += 128 * 4;
    float* shiftV = (float*)w;    w += 128 * 4;
    float* c0v    = (float*)w;    w += 128 * 4;
    int* hitList = (int*)w;       w += (size_t)N * 4;
    int* ucode   = (int*)w;       w += (size_t)N * 4;
    int* slotA   = (int*)w;       w += (size_t)N * 4;
    int* bkUid   = (int*)w;       w += (size_t)KK * CAPK * 4;
    int* bkP     = (int*)w;       w += (size_t)KK * CAPK * 4;
    int* pairPack= (int*)w;       w += (size_t)PP * CAPP * 4;
    float* acc   = (float*)w;     w += (size_t)N * CC * 4;     // 89.9 MB

    hipMemsetAsync(tabB, 0xFF, ffbytes, stream);
    hipMemsetAsync(zero0, 0, zbytes, stream);

    int nbA = (N + 255) / 256;        // 686
    int nbB = (Nv + 255) / 256;       // 782
    k_buildInsert<<<nbA + nbB, 256, 0, stream>>>(gp, tabA, slotA, nq, ucode, N, nbA,
                                                 (const int4*)spc, tabB, colBM, Nv);
    long tot = (long)N * 25;
    k_probe  <<<(unsigned)((tot + 255) / 256), 256, 0, stream>>>(ucode, colBM, tabB,
                                                                 (const int4*)spc,
                                                                 hmark, cntk, bkUid, bkP, nq, N);
    int nbU = (N + 255) / 256;        // covers all possible uids
    k_hitPairs<<<nbU + nbA, 256, 0, stream>>>(hmark, hitList, nh, acc, nq, nbU,
                                              slotA, tabA, pcnt, pairPack, N);
    k_conv   <<<dim3(KK, 2, 4), 256, 0, stream>>>(spf, W1, cntk, bkUid, bkP, acc);
    k_stats  <<<256, 256, 0, stream>>>(acc, hitList, gsum, gsumsq, nh, done,
                                       g1, b1, scaleV, shiftV, c0v, nq);
    k_pool   <<<dim3(PP, 2, 2), 256, 0, stream>>>(acc, W2, pcnt, pairPack,
                                                  scaleV, shiftV, c0v, pooled);
    k_bn2    <<<CC, 64, 0, stream>>>(pooled, g2, b2, out, NB);
}